// Round 6
// baseline (184.874 us; speedup 1.0000x reference)
//
#include <hip/hip_runtime.h>
#include <math.h>

// Problem constants: 20 qubits, B=16 batch, RX chain on qubit 0,
// 2-qubit Hamiltonian evolution on qubits (2,5), observable = sum_q Z_q.
// State layout: (dim, B) row-major => flat idx = i*B + b; qubit q bit of i is at
// bit position (19 - q). So qubit 0 -> bit 19, qubit 2 -> bit 17, qubit 5 -> bit 14.
constexpr int NQ     = 20;
constexpr int DIM    = 1 << NQ;
constexpr int B      = 16;
constexpr int GROUPS = 1 << 17;   // DIM / 8 (octets over bits 19,17,14)
constexpr int GPB    = 32;        // groups per block
constexpr int NBLK   = GROUPS / GPB;   // 4096
constexpr int NTHR   = 512;       // one (group, batch) pair per thread: 32*16

// ws layout (floats):
//   [0..15]    cos(0.5*sum theta) per batch
//   [16..31]   sin(0.5*sum theta) per batch
//   [32..543]  Ue per batch: b*32 + (i*4+j)*2 (+1 imag)

// ---- Prep: parallelized across 256 threads = 16 batches x 16 matrix elements.
// expm(-i t H) via fp64 scaling-squaring with LDS ping-pong for the 4x4 products.
__global__ __launch_bounds__(256) void prep_kernel(
    const float* __restrict__ hre, const float* __restrict__ him,
    const float* __restrict__ theta, const float* __restrict__ tv,
    float* __restrict__ ws, float* __restrict__ out) {
  __shared__ double Mre[16][16], Mim[16][16];
  __shared__ double Are[16][16], Aim[16][16];   // ping
  __shared__ double Bre[16][16], Bim[16][16];   // pong
  __shared__ double nrm[16][4];
  __shared__ int    scl[16];
  __shared__ int    scmax_s;

  int t = threadIdx.x;
  int b = t >> 4, e = t & 15, i = e >> 2, j = e & 3;

  if (t < 16) out[t] = 0.f;       // zero the global accumulators each replay
  if (t == 0) scmax_s = 0;

  // RX coeffs: all RX on the same qubit commute => product = RX(sum theta).
  if (e == 0) {
    double th = 0.0;
    for (int k = 0; k < 8; k++) th += (double)theta[k * B + b];
    th *= 0.5;
    ws[b]     = (float)cos(th);
    ws[B + b] = (float)sin(th);
  }

  // H = 0.5*(A + A^H);  M = -i * t * H  =>  Mre = t*Him, Mim = -t*Hre
  {
    double tt  = (double)tv[b];
    double are = hre[(i*4+j)*B + b], aim = him[(i*4+j)*B + b];
    double cre = hre[(j*4+i)*B + b], cim = him[(j*4+i)*B + b];
    double Hre = 0.5*(are + cre), Him = 0.5*(aim - cim);
    Mre[b][e] = tt * Him;
    Mim[b][e] = -tt * Hre;
  }
  __syncthreads();

  // inf-norm upper bound: row sums, then max; per-batch scaling exponent
  if (j == 0) {
    double r = 0.0;
    for (int m = 0; m < 4; m++) r += fabs(Mre[b][i*4+m]) + fabs(Mim[b][i*4+m]);
    nrm[b][i] = r;
  }
  __syncthreads();
  if (e == 0) {
    double ninf = fmax(fmax(nrm[b][0], nrm[b][1]), fmax(nrm[b][2], nrm[b][3]));
    int sc = 0;
    while (ninf > 0.25 && sc < 40) { ninf *= 0.5; sc++; }
    scl[b] = sc;
    atomicMax(&scmax_s, sc);
  }
  __syncthreads();
  int sc = scl[b];
  int scmax = scmax_s;
  {
    double scale = ldexp(1.0, -sc);
    Mre[b][e] *= scale; Mim[b][e] *= scale;
  }
  // T = I
  Are[b][e] = (i == j) ? 1.0 : 0.0;
  Aim[b][e] = 0.0;
  __syncthreads();

  double (*Tr)[16] = Are; double (*Ti)[16] = Aim;
  double (*Pr)[16] = Bre; double (*Pi)[16] = Bim;

  // Taylor via Horner: for k=13..1: T = I + M*T/k   (each thread owns one element)
  for (int k = 13; k >= 1; k--) {
    double rr = 0.0, ii = 0.0;
    for (int m = 0; m < 4; m++) {
      double mr = Mre[b][i*4+m], mi = Mim[b][i*4+m];
      double xr = Tr[b][m*4+j],  xi = Ti[b][m*4+j];
      rr += mr*xr - mi*xi;
      ii += mr*xi + mi*xr;
    }
    double inv = 1.0 / (double)k;
    Pr[b][e] = rr*inv + ((i == j) ? 1.0 : 0.0);
    Pi[b][e] = ii*inv;
    { double (*s)[16] = Tr; Tr = Pr; Pr = s; s = Ti; Ti = Pi; Pi = s; }
    __syncthreads();
  }
  // Squaring (uniform scmax iterations; batches with q >= sc just copy forward)
  for (int q = 0; q < scmax; q++) {
    double rr, ii;
    if (q < sc) {
      rr = 0.0; ii = 0.0;
      for (int m = 0; m < 4; m++) {
        double xr = Tr[b][i*4+m], xi = Ti[b][i*4+m];
        double yr = Tr[b][m*4+j], yi = Ti[b][m*4+j];
        rr += xr*yr - xi*yi;
        ii += xr*yi + xi*yr;
      }
    } else { rr = Tr[b][e]; ii = Ti[b][e]; }
    Pr[b][e] = rr; Pi[b][e] = ii;
    { double (*s)[16] = Tr; Tr = Pr; Pr = s; s = Ti; Ti = Pi; Pi = s; }
    __syncthreads();
  }

  float* ue = ws + 2*B + b*32;
  ue[e*2]     = (float)Tr[b][e];
  ue[e*2 + 1] = (float)Ti[b][e];
}

// ---- Fused gate-apply + expectation, LDS-staged (GEMM-style decoupling).
// Rounds 1-4: per-component source structure let the compiler split every wide
// load into scalar dword passes (VGPR=52, issue/latency-bound at ~45us; replay
// dispatches prove it's NOT BW-bound: hbm_bytes~0 with L3-resident input, same
// time). Fix: stage state through LDS. Each block owns 32 consecutive groups;
// the 8 octet offsets x {re,im} form 16 CONTIGUOUS 2KB panels (32 rows x 16
// batches). Staging loads feed ds_write_b128 as whole float4s -> the register
// allocator has no component-split option. Compute = verbatim round-0 scalar
// math (verified), one (group,batch) per thread, conflict-free LDS reads.
__global__ __launch_bounds__(NTHR) void fused_kernel(
    const float* __restrict__ sre, const float* __restrict__ sim,
    const float* __restrict__ ws, float* __restrict__ out) {
  __shared__ float st[16 * 512];   // panel p = 2*j + (im?1:0); word = p*512 + r*16 + b
  __shared__ float red[16];

  int t = threadIdx.x;
  int g0 = blockIdx.x * GPB;       // 32-aligned => low 5 bits of g0 are zero
  int base0 = (g0 & 0x3FFF) | ((g0 & 0xC000) << 1) | ((g0 & 0x10000) << 2);

  // ---- Stage 32 KB: 2048 16B-chunks, 4 per thread, fully coalesced ----
  #pragma unroll
  for (int p = 0; p < 4; p++) {
    int ci    = p * 512 + t;       // chunk id 0..2047
    int panel = ci >> 7;           // 0..15 (128 chunks = 2KB per panel)
    int w     = (ci & 127) << 2;   // word offset within panel
    int j     = panel >> 1;
    const float* src = (panel & 1) ? sim : sre;
    int off = ((((j >> 2) & 1) << 19) | (((j >> 1) & 1) << 17) | ((j & 1) << 14));
    float4 v = *(const float4*)(src + (base0 + off) * 16 + w);
    *(float4*)&st[panel * 512 + w] = v;
  }
  if (t < 16) red[t] = 0.f;

  // ---- Per-thread constants: batch b, local group gl; U in registers (L1-hot ws) ----
  int b  = t & 15;
  int gl = t >> 4;                 // 0..31
  float c = ws[b], s = ws[B + b];
  float ur[4][4], ui[4][4];
  {
    const float* ue = ws + 2 * B + b * 32;
    #pragma unroll
    for (int i = 0; i < 4; i++) {
      float4 p0 = *(const float4*)(ue + i * 8);      // ur0,ui0,ur1,ui1
      float4 p1 = *(const float4*)(ue + i * 8 + 4);  // ur2,ui2,ur3,ui3
      ur[i][0] = p0.x; ui[i][0] = p0.y; ur[i][1] = p0.z; ui[i][1] = p0.w;
      ur[i][2] = p1.x; ui[i][2] = p1.y; ur[i][3] = p1.z; ui[i][3] = p1.w;
    }
  }
  __syncthreads();

  // ---- State for this (group, batch): 16 conflict-free scalar LDS reads ----
  // address = panel*512 + gl*16 + b = panel*512 + t  (lane-consecutive dwords)
  float ar[8], ai[8];
  #pragma unroll
  for (int j = 0; j < 8; j++) {
    ar[j] = st[(2 * j) * 512 + t];
    ai[j] = st[(2 * j + 1) * 512 + t];
  }

  // ---- RX(theta_sum) on qubit 0 (bit j>>2): pairs (j, j+4) ----
  #pragma unroll
  for (int j = 0; j < 4; j++) {
    float xr = ar[j], xi = ai[j], yr = ar[j+4], yi = ai[j+4];
    ar[j]   = c*xr + s*yi;   ai[j]   = c*xi - s*yr;
    ar[j+4] = s*xi + c*yr;   ai[j+4] = c*yi - s*xr;
  }

  // ---- Ue on (qubit2,qubit5) + weight-folded |amp|^2 (verbatim round-0 body) ----
  int base = base0 + gl;           // gl fits in zeroed low bits, no carry
  int pc = __popc(base);
  float wb = (float)(17 - 2*pc);
  float acc = 0.f;
  #pragma unroll
  for (int h = 0; h < 2; h++) {
    float w0 = wb + (h ? -1.f : 1.f);
    #pragma unroll
    for (int k = 0; k < 4; k++) {
      float rr = 0.f, ii = 0.f;
      #pragma unroll
      for (int m = 0; m < 4; m++) {
        float xr = ar[h*4+m], xi = ai[h*4+m];
        rr = fmaf(ur[k][m], xr, rr); rr = fmaf(-ui[k][m], xi, rr);
        ii = fmaf(ur[k][m], xi, ii); ii = fmaf(ui[k][m], xr, ii);
      }
      int sb = ((k>>1)&1) + (k&1);
      float w = w0 + (float)(2 - 2*sb);
      acc = fmaf(rr*rr + ii*ii, w, acc);
    }
  }

  // ---- Reduce: lanes {l, l^16, l^32, l^48} share b => butterfly over bits 4,5 ----
  acc += __shfl_xor(acc, 16, 64);
  acc += __shfl_xor(acc, 32, 64);

  if ((t & 63) < 16) atomicAdd(&red[t & 15], acc);
  __syncthreads();
  // one global atomic per (block, batch); blocks retire staggered => contention hidden
  if (t < 16) atomicAdd(&out[t], red[t]);
}

extern "C" void kernel_launch(void* const* d_in, const int* in_sizes, int n_in,
                              void* d_out, int out_size, void* d_ws, size_t ws_size,
                              hipStream_t stream) {
  const float* sre = (const float*)d_in[0];
  const float* sim = (const float*)d_in[1];
  const float* hre = (const float*)d_in[2];
  const float* him = (const float*)d_in[3];
  const float* th  = (const float*)d_in[4];
  const float* tv  = (const float*)d_in[5];

  float* ws = (float*)d_ws;
  float* out = (float*)d_out;

  prep_kernel<<<1, 256, 0, stream>>>(hre, him, th, tv, ws, out);
  fused_kernel<<<NBLK, NTHR, 0, stream>>>(sre, sim, ws, out);
}

// Round 7
// 177.735 us; speedup vs baseline: 1.0402x; 1.0402x over previous
//
#include <hip/hip_runtime.h>
#include <math.h>

// Problem constants: 20 qubits, B=16 batch, RX chain on qubit 0,
// 2-qubit Hamiltonian evolution on qubits (2,5), observable = sum_q Z_q.
// State layout: (dim, B) row-major => flat idx = i*B + b; qubit q bit of i is at
// bit position (19 - q). So qubit 0 -> bit 19, qubit 2 -> bit 17, qubit 5 -> bit 14.
constexpr int NQ     = 20;
constexpr int DIM    = 1 << NQ;
constexpr int B      = 16;
constexpr int GROUPS = 1 << 17;       // DIM / 8 (octets over bits 19,17,14)
constexpr int GPB    = 32;            // groups per tile (one LDS tile = 32 KB)
constexpr int TILES  = GROUPS / GPB;  // 4096
constexpr int NBLK   = 1024;
constexpr int TPB    = TILES / NBLK;  // 4 consecutive tiles per block
constexpr int NTHR   = 512;          // one (group, batch) pair per thread per tile

// ws layout (floats):
//   [0..15]    cos(0.5*sum theta) per batch
//   [16..31]   sin(0.5*sum theta) per batch
//   [32..543]  Ue per batch: b*32 + (i*4+j)*2 (+1 imag)
//   [544..]    per-block partials: NBLK*16 floats  (same footprint as round 0)

// ---- Prep: parallelized across 256 threads = 16 batches x 16 matrix elements.
// expm(-i t H) via fp64 scaling-squaring with LDS ping-pong for the 4x4 products.
__global__ __launch_bounds__(256) void prep_kernel(
    const float* __restrict__ hre, const float* __restrict__ him,
    const float* __restrict__ theta, const float* __restrict__ tv,
    float* __restrict__ ws) {
  __shared__ double Mre[16][16], Mim[16][16];
  __shared__ double Are[16][16], Aim[16][16];   // ping
  __shared__ double Bre[16][16], Bim[16][16];   // pong
  __shared__ double nrm[16][4];
  __shared__ int    scl[16];
  __shared__ int    scmax_s;

  int t = threadIdx.x;
  int b = t >> 4, e = t & 15, i = e >> 2, j = e & 3;

  if (t == 0) scmax_s = 0;

  // RX coeffs: all RX on the same qubit commute => product = RX(sum theta).
  if (e == 0) {
    double th = 0.0;
    for (int k = 0; k < 8; k++) th += (double)theta[k * B + b];
    th *= 0.5;
    ws[b]     = (float)cos(th);
    ws[B + b] = (float)sin(th);
  }

  // H = 0.5*(A + A^H);  M = -i * t * H  =>  Mre = t*Him, Mim = -t*Hre
  {
    double tt  = (double)tv[b];
    double are = hre[(i*4+j)*B + b], aim = him[(i*4+j)*B + b];
    double cre = hre[(j*4+i)*B + b], cim = him[(j*4+i)*B + b];
    double Hre = 0.5*(are + cre), Him = 0.5*(aim - cim);
    Mre[b][e] = tt * Him;
    Mim[b][e] = -tt * Hre;
  }
  __syncthreads();

  // inf-norm upper bound: row sums, then max; per-batch scaling exponent
  if (j == 0) {
    double r = 0.0;
    for (int m = 0; m < 4; m++) r += fabs(Mre[b][i*4+m]) + fabs(Mim[b][i*4+m]);
    nrm[b][i] = r;
  }
  __syncthreads();
  if (e == 0) {
    double ninf = fmax(fmax(nrm[b][0], nrm[b][1]), fmax(nrm[b][2], nrm[b][3]));
    int sc = 0;
    while (ninf > 0.25 && sc < 40) { ninf *= 0.5; sc++; }
    scl[b] = sc;
    atomicMax(&scmax_s, sc);
  }
  __syncthreads();
  int sc = scl[b];
  int scmax = scmax_s;
  {
    double scale = ldexp(1.0, -sc);
    Mre[b][e] *= scale; Mim[b][e] *= scale;
  }
  // T = I
  Are[b][e] = (i == j) ? 1.0 : 0.0;
  Aim[b][e] = 0.0;
  __syncthreads();

  double (*Tr)[16] = Are; double (*Ti)[16] = Aim;
  double (*Pr)[16] = Bre; double (*Pi)[16] = Bim;

  // Taylor via Horner: for k=13..1: T = I + M*T/k   (each thread owns one element)
  for (int k = 13; k >= 1; k--) {
    double rr = 0.0, ii = 0.0;
    for (int m = 0; m < 4; m++) {
      double mr = Mre[b][i*4+m], mi = Mim[b][i*4+m];
      double xr = Tr[b][m*4+j],  xi = Ti[b][m*4+j];
      rr += mr*xr - mi*xi;
      ii += mr*xi + mi*xr;
    }
    double inv = 1.0 / (double)k;
    Pr[b][e] = rr*inv + ((i == j) ? 1.0 : 0.0);
    Pi[b][e] = ii*inv;
    { double (*s)[16] = Tr; Tr = Pr; Pr = s; s = Ti; Ti = Pi; Pi = s; }
    __syncthreads();
  }
  // Squaring (uniform scmax iterations; batches with q >= sc just copy forward)
  for (int q = 0; q < scmax; q++) {
    double rr, ii;
    if (q < sc) {
      rr = 0.0; ii = 0.0;
      for (int m = 0; m < 4; m++) {
        double xr = Tr[b][i*4+m], xi = Ti[b][i*4+m];
        double yr = Tr[b][m*4+j], yi = Ti[b][m*4+j];
        rr += xr*yr - xi*yi;
        ii += xr*yi + xi*yr;
      }
    } else { rr = Tr[b][e]; ii = Ti[b][e]; }
    Pr[b][e] = rr; Pi[b][e] = ii;
    { double (*s)[16] = Tr; Tr = Pr; Pr = s; s = Ti; Ti = Pi; Pi = s; }
    __syncthreads();
  }

  float* ue = ws + 2*B + b*32;
  ue[e*2]     = (float)Tr[b][e];
  ue[e*2 + 1] = (float)Ti[b][e];
}

// ---- Fused gate-apply + expectation: async LDS staging + grid-stride tiles.
// Root cause from rounds 1-6: the compiler crushes VGPRs toward max occupancy
// (32-56 observed) which serializes any reg-staged wide-load pattern; the kernel
// is latency-bound (replay dispatches with ZERO HBM traffic run identical times).
// Fix: __builtin_amdgcn_global_load_lds (async, width=16) — staging bypasses
// VGPRs entirely, so register pressure cannot serialize it. Each wave issues 4
// async 1KB copies back-to-back; __syncthreads() drains vmcnt before s_barrier
// (m97-verified compiler behavior). LDS layout is byte-identical to the verified
// round-6 staging, so the verified compute body is reused unchanged. The global
// atomic tail (32-65K same-line atomicAdds ~ tens of us serialized) is replaced
// by per-block partial writes + a reduce kernel (round-0-verified).
__global__ __launch_bounds__(NTHR, 6) void fused_kernel(
    const float* __restrict__ sre, const float* __restrict__ sim,
    const float* __restrict__ ws, float* __restrict__ partial) {
  __shared__ float st[16 * 512];   // panel p = 2*j + (im?1:0); word = p*512 + r*16 + b
  __shared__ float red[16];

  int t = threadIdx.x;
  if (t < 16) red[t] = 0.f;

  // ---- Per-thread constants: batch b, local group gl; U in registers (L1-hot ws)
  int b  = t & 15;
  int gl = t >> 4;                 // 0..31
  float c = ws[b], s = ws[B + b];
  float ur[4][4], ui[4][4];
  {
    const float* ue = ws + 2 * B + b * 32;
    #pragma unroll
    for (int i = 0; i < 4; i++) {
      float4 p0 = *(const float4*)(ue + i * 8);      // ur0,ui0,ur1,ui1
      float4 p1 = *(const float4*)(ue + i * 8 + 4);  // ur2,ui2,ur3,ui3
      ur[i][0] = p0.x; ui[i][0] = p0.y; ur[i][1] = p0.z; ui[i][1] = p0.w;
      ur[i][2] = p1.x; ui[i][2] = p1.y; ur[i][3] = p1.z; ui[i][3] = p1.w;
    }
  }

  int l  = t & 63;                 // lane
  int wv = t >> 6;                 // wave id 0..7
  float acc = 0.f;

  for (int tt = 0; tt < TPB; tt++) {
    int g0 = (blockIdx.x * TPB + tt) * GPB;   // 32-aligned => low 5 bits zero
    int base0 = (g0 & 0x3FFF) | ((g0 & 0xC000) << 1) | ((g0 & 0x10000) << 2);

    // ---- Stage 32 KB via async global->LDS: 4 x 1KB per wave, no VGPR use ----
    #pragma unroll
    for (int p = 0; p < 4; p++) {
      int cb    = p * 512 + wv * 64;   // wave-uniform chunk base (64-aligned)
      int panel = cb >> 7;             // 0..15; 64 chunks stay inside one panel
      int wofs  = (cb & 127) << 2;     // word offset within panel
      int j     = panel >> 1;
      const float* src = (panel & 1) ? sim : sre;
      int off = (((j >> 2) & 1) << 19) | (((j >> 1) & 1) << 17) | ((j & 1) << 14);
      const float* gsrc = src + (size_t)(base0 + off) * 16 + wofs + l * 4; // 16B/lane
      float* ldst = &st[panel * 512 + wofs];   // wave-uniform; HW adds lane*16B
      __builtin_amdgcn_global_load_lds(
          (const __attribute__((address_space(1))) void*)gsrc,
          (__attribute__((address_space(3))) void*)ldst,
          16, 0, 0);
    }
    __syncthreads();   // compiler drains vmcnt(0) before s_barrier: tile visible

    // ---- State for this (group, batch): 16 conflict-free scalar LDS reads ----
    // address = panel*512 + gl*16 + b = panel*512 + t (lane-consecutive dwords)
    float ar[8], ai[8];
    #pragma unroll
    for (int j = 0; j < 8; j++) {
      ar[j] = st[(2 * j) * 512 + t];
      ai[j] = st[(2 * j + 1) * 512 + t];
    }

    // ---- RX(theta_sum) on qubit 0 (bit j>>2): pairs (j, j+4) ----
    #pragma unroll
    for (int j = 0; j < 4; j++) {
      float xr = ar[j], xi = ai[j], yr = ar[j+4], yi = ai[j+4];
      ar[j]   = c*xr + s*yi;   ai[j]   = c*xi - s*yr;
      ar[j+4] = s*xi + c*yr;   ai[j+4] = c*yi - s*xr;
    }

    // ---- Ue on (qubit2,qubit5) + weight-folded |amp|^2 (verified body) ----
    int base = base0 + gl;           // gl fits in zeroed low bits, no carry
    int pc = __popc(base);
    float wb = (float)(17 - 2*pc);
    #pragma unroll
    for (int h = 0; h < 2; h++) {
      float w0 = wb + (h ? -1.f : 1.f);
      #pragma unroll
      for (int k = 0; k < 4; k++) {
        float rr = 0.f, ii = 0.f;
        #pragma unroll
        for (int m = 0; m < 4; m++) {
          float xr = ar[h*4+m], xi = ai[h*4+m];
          rr = fmaf(ur[k][m], xr, rr); rr = fmaf(-ui[k][m], xi, rr);
          ii = fmaf(ur[k][m], xi, ii); ii = fmaf(ui[k][m], xr, ii);
        }
        int sb = ((k>>1)&1) + (k&1);
        float w = w0 + (float)(2 - 2*sb);
        acc = fmaf(rr*rr + ii*ii, w, acc);
      }
    }
    __syncthreads();   // tile fully consumed before next staging overwrites st
  }

  // ---- Reduce: lanes {l, l^16, l^32, l^48} share b => butterfly over bits 4,5 ----
  acc += __shfl_xor(acc, 16, 64);
  acc += __shfl_xor(acc, 32, 64);

  if ((t & 63) < 16) atomicAdd(&red[t & 15], acc);
  __syncthreads();
  if (t < 16) partial[blockIdx.x * 16 + t] = red[t];   // coalesced 64B store
}

// ---- Final reduction over per-block partials ----
__global__ void reduce_kernel(const float* __restrict__ partial, float* __restrict__ out) {
  int t = threadIdx.x;       // 256 threads
  int b = t & 15;
  float acc = 0.f;
  for (int i = t >> 4; i < NBLK; i += 16)
    acc += partial[i * 16 + b];
  acc += __shfl_xor(acc, 16, 64);
  acc += __shfl_xor(acc, 32, 64);
  __shared__ float red[16];
  if (t < 16) red[t] = 0.f;
  __syncthreads();
  if ((t & 63) < 16) atomicAdd(&red[t & 15], acc);
  __syncthreads();
  if (t < 16) out[t] = red[t];
}

extern "C" void kernel_launch(void* const* d_in, const int* in_sizes, int n_in,
                              void* d_out, int out_size, void* d_ws, size_t ws_size,
                              hipStream_t stream) {
  const float* sre = (const float*)d_in[0];
  const float* sim = (const float*)d_in[1];
  const float* hre = (const float*)d_in[2];
  const float* him = (const float*)d_in[3];
  const float* th  = (const float*)d_in[4];
  const float* tv  = (const float*)d_in[5];

  float* ws = (float*)d_ws;
  float* partial = ws + 544;

  prep_kernel<<<1, 256, 0, stream>>>(hre, him, th, tv, ws);
  fused_kernel<<<NBLK, NTHR, 0, stream>>>(sre, sim, ws, partial);
  reduce_kernel<<<1, 256, 0, stream>>>(partial, (float*)d_out);
}